// Round 2
// baseline (94387.628 us; speedup 1.0000x reference)
//
#include <hip/hip_runtime.h>
#include <math.h>

#define HDIM 256
#define BATCH 64
#define TLEN 512
#define IDIM 64

// ---------------- ws layout (float offsets) ----------------
static const size_t OFF_XG    = 0;
static const size_t OFF_YA    = 33554432;
static const size_t OFF_YB    = OFF_YA + 8388608;
static const size_t OFF_WIHT  = OFF_YB + 8388608;
static const size_t OFF_WHHT  = OFF_WIHT + 1048576;
static const size_t OFF_BSUM  = OFF_WHHT + 1048576;
static const size_t OFF_STATE = OFF_BSUM + 4096;

__device__ __forceinline__ float sig_(float x) { return 1.f / (1.f + __expf(-x)); }
// safe fast tanh: x->+inf => 1, x->-inf => -1 (no inf/inf NaN)
__device__ __forceinline__ float tanh_(float x) { float e = __expf(2.f * x); return 1.f - 2.f / (e + 1.f); }

union U4 { float4 v; float f[4]; };

// -------- prep: weight re-layouts --------
__global__ void prep_wih(const float* __restrict__ w, float* __restrict__ wt, int K) {
    int idx = blockIdx.x * 256 + threadIdx.x;
    if (idx >= 1024 * K) return;
    int n = idx / K, k = idx - n * K;
    int j = n >> 2, g = n & 3;
    wt[idx] = w[(g * 256 + j) * K + k];
}

__global__ void prep_whh(const float* __restrict__ w, float* __restrict__ wt) {
    int idx = blockIdx.x * 256 + threadIdx.x;   // 262144 per layer
    int k = idx >> 10, r = idx & 1023;
    int j = r >> 2, g = r & 3;
    wt[idx] = w[(g * 256 + j) * 256 + k];
}

__global__ void prep_bias(const float* __restrict__ bi, const float* __restrict__ bh,
                          float* __restrict__ bs) {
    int n = blockIdx.x * 256 + threadIdx.x;     // 1024
    int j = n >> 2, g = n & 3;
    bs[n] = bi[g * 256 + j] + bh[g * 256 + j];
}

// -------- projection GEMM (unchanged from round 1) --------
__global__ __launch_bounds__(256) void proj_kernel(
    const float* __restrict__ A, int K, int doRelu,
    const float* __restrict__ Wt, const float* __restrict__ bsum,
    float* __restrict__ out)
{
    __shared__ float As[16][128];
    __shared__ float Bs[16][128];
    const int tid = threadIdx.x;
    const int m0 = blockIdx.x * 128;
    const int n0 = blockIdx.y * 128;
    const int tx = tid & 15, ty = tid >> 4;

    float acc[8][8];
#pragma unroll
    for (int i = 0; i < 8; ++i)
#pragma unroll
        for (int j = 0; j < 8; ++j) acc[i][j] = 0.f;

    for (int kt = 0; kt < K; kt += 16) {
#pragma unroll
        for (int l = 0; l < 2; ++l) {
            int f = tid * 2 + l;
            int r = f >> 2;
            int c = (f & 3) << 2;
            float4 v = *(const float4*)&A[(size_t)(m0 + r) * K + kt + c];
            if (doRelu) {
                v.x = fmaxf(v.x, 0.f); v.y = fmaxf(v.y, 0.f);
                v.z = fmaxf(v.z, 0.f); v.w = fmaxf(v.w, 0.f);
            }
            As[c + 0][r] = v.x; As[c + 1][r] = v.y; As[c + 2][r] = v.z; As[c + 3][r] = v.w;
            float4 w = *(const float4*)&Wt[(size_t)(n0 + r) * K + kt + c];
            Bs[c + 0][r] = w.x; Bs[c + 1][r] = w.y; Bs[c + 2][r] = w.z; Bs[c + 3][r] = w.w;
        }
        __syncthreads();
#pragma unroll
        for (int kk = 0; kk < 16; ++kk) {
            float a[8], bb[8];
            *(float4*)&a[0]  = *(const float4*)&As[kk][ty * 8];
            *(float4*)&a[4]  = *(const float4*)&As[kk][ty * 8 + 4];
            *(float4*)&bb[0] = *(const float4*)&Bs[kk][tx * 8];
            *(float4*)&bb[4] = *(const float4*)&Bs[kk][tx * 8 + 4];
#pragma unroll
            for (int i = 0; i < 8; ++i)
#pragma unroll
                for (int j = 0; j < 8; ++j) acc[i][j] = fmaf(a[i], bb[j], acc[i][j]);
        }
        __syncthreads();
    }

    float bsv[8];
#pragma unroll
    for (int j = 0; j < 8; ++j) bsv[j] = bsum[n0 + tx * 8 + j];
#pragma unroll
    for (int i = 0; i < 8; ++i) {
        size_t row = (size_t)(m0 + ty * 8 + i);
        float4 o1 = { acc[i][0] + bsv[0], acc[i][1] + bsv[1], acc[i][2] + bsv[2], acc[i][3] + bsv[3] };
        float4 o2 = { acc[i][4] + bsv[4], acc[i][5] + bsv[5], acc[i][6] + bsv[6], acc[i][7] + bsv[7] };
        *(float4*)&out[row * 1024 + n0 + tx * 8]     = o1;
        *(float4*)&out[row * 1024 + n0 + tx * 8 + 4] = o2;
    }
}

// -------- recurrence v2: latency-hidden, balanced halves --------
// 32 WGs x 512 threads. thread=(j 0..255, half 0/1). half h reduces k in
// [128h,128h+128) for BOTH batches, owns activations for batch b0+half.
// Weights: chunk kb 0..15 persistent in VGPRs (loaded once, reused 512 steps);
// kb 16..127 streamed through 3 rotating 8-float4 register buffers (2 chunks
// in flight ~500+cy covers L2 ~300cy latency). h read via wave-uniform LDS
// broadcast (no per-lane LDS BW floor).

#define LD8(DST, KB) { _Pragma("unroll") for (int u = 0; u < 8; ++u) \
    DST[u] = *(const float4*)(wb + (size_t)((KB) + u) * 1024); }

#define FM8(SRC, KB) { _Pragma("unroll") for (int q = 0; q < 2; ++q) { \
    U4 h0u, h1u; \
    h0u.v = *(const float4*)&hc0[(KB) + q * 4]; \
    h1u.v = *(const float4*)&hc1[(KB) + q * 4]; \
    _Pragma("unroll") for (int u = 0; u < 4; ++u) { \
      float4 w = (SRC)[q * 4 + u]; float a_ = h0u.f[u], b_ = h1u.f[u]; \
      ai0 = fmaf(w.x, a_, ai0); af0 = fmaf(w.y, a_, af0); \
      ag0 = fmaf(w.z, a_, ag0); ao0 = fmaf(w.w, a_, ao0); \
      ai1 = fmaf(w.x, b_, ai1); af1 = fmaf(w.y, b_, af1); \
      ag1 = fmaf(w.z, b_, ag1); ao1 = fmaf(w.w, b_, ao1); } } }

__global__ __launch_bounds__(512, 2) void rec_kernel(
    const float* __restrict__ xg4,    // [64][512][1024] gate-interleaved
    const float* __restrict__ whhT4,  // [256 k][256 j][4 g]
    float* __restrict__ y,            // [64][512][256]
    const float* __restrict__ h_init, const float* __restrict__ c_init,
    float* __restrict__ h_save, float* __restrict__ c_save)
{
    __shared__ __align__(16) float hsm[2][2][HDIM];
    __shared__ __align__(16) float psum[8][HDIM];
    const int tid  = threadIdx.x;
    const int j    = tid & (HDIM - 1);
    const int half = tid >> 8;
    const int bb   = blockIdx.x * 2 + half;   // own batch

    float c = 0.f, hprev = 0.f;
    if (h_init != nullptr) {
        hprev = h_init[bb * HDIM + j];
        c     = c_init[bb * HDIM + j];
    }
    hsm[0][half][j] = hprev;

    const float* wb = whhT4 + (size_t)(half * 128) * 1024 + j * 4;

    // persistent weight chunk: kb 0..15 (never re-fetched)
    float4 wP[16];
#pragma unroll
    for (int u = 0; u < 16; ++u) wP[u] = *(const float4*)(wb + (size_t)u * 1024);

    __syncthreads();

    int cur = 0;
    for (int t = 0; t < TLEN; ++t) {
        const int nxt = cur ^ 1;
        // own-batch x-gates: independent, issue early
        float4 xv = *(const float4*)&xg4[((size_t)bb * TLEN + t) * 1024 + j * 4];

        const float* hc0 = &hsm[cur][0][half * 128];
        const float* hc1 = &hsm[cur][1][half * 128];

        float ai0 = 0.f, af0 = 0.f, ag0 = 0.f, ao0 = 0.f;
        float ai1 = 0.f, af1 = 0.f, ag1 = 0.f, ao1 = 0.f;

        float4 wA[8], wB[8], wC[8];
        LD8(wA, 16); LD8(wB, 24);          // 2 chunks in flight
        FM8(wP + 0, 0); FM8(wP + 8, 8);    // compute on persistent chunk meanwhile
        LD8(wC, 32); FM8(wA, 16);
        LD8(wA, 40); FM8(wB, 24);
        LD8(wB, 48); FM8(wC, 32);
        LD8(wC, 56); FM8(wA, 40);
        LD8(wA, 64); FM8(wB, 48);
        LD8(wB, 72); FM8(wC, 56);
        LD8(wC, 80); FM8(wA, 64);
        LD8(wA, 88); FM8(wB, 72);
        LD8(wB, 96); FM8(wC, 80);
        LD8(wC, 104); FM8(wA, 88);
        LD8(wA, 112); FM8(wB, 96);
        LD8(wB, 120); FM8(wC, 104);
        FM8(wA, 112);
        FM8(wB, 120);

        // ship partials of the OTHER half's batch
        if (half == 0) {
            psum[0][j] = ai1; psum[1][j] = af1; psum[2][j] = ag1; psum[3][j] = ao1;
        } else {
            psum[4][j] = ai0; psum[5][j] = af0; psum[6][j] = ag0; psum[7][j] = ao0;
        }
        __syncthreads();

        // combine own-batch partials + received + x-gates
        float si = (half ? ai1 : ai0) + psum[(half ^ 1) * 4 + 0][j] + xv.x;
        float sf = (half ? af1 : af0) + psum[(half ^ 1) * 4 + 1][j] + xv.y;
        float sg = (half ? ag1 : ag0) + psum[(half ^ 1) * 4 + 2][j] + xv.z;
        float so = (half ? ao1 : ao0) + psum[(half ^ 1) * 4 + 3][j] + xv.w;

        float ig = sig_(si);
        float fg = sig_(sf);
        float gg = tanh_(sg);
        float og = sig_(so);
        c = fmaf(fg, c, ig * gg);
        float hn = og * tanh_(c);
        hprev = hn;

        y[((size_t)bb * TLEN + t) * HDIM + j] = hn;
        hsm[nxt][half][j] = hn;
        __syncthreads();
        cur = nxt;
    }

    if (h_save != nullptr) {
        h_save[bb * HDIM + j] = hprev;
        c_save[bb * HDIM + j] = c;
    }
}

// -------- head --------
__global__ __launch_bounds__(256) void head_kernel(const float* __restrict__ y3,
    const float* __restrict__ lin_w, const float* __restrict__ lin_b, float* __restrict__ out)
{
    int b = blockIdx.x;
    int tid = threadIdx.x;
    float v = y3[((size_t)b * TLEN + (TLEN - 1)) * HDIM + tid] * lin_w[tid];
#pragma unroll
    for (int o = 32; o > 0; o >>= 1) v += __shfl_down(v, o);
    __shared__ float red[4];
    int wid = tid >> 6, lane = tid & 63;
    if (lane == 0) red[wid] = v;
    __syncthreads();
    if (tid == 0) out[b] = red[0] + red[1] + red[2] + red[3] + lin_b[0];
}

extern "C" void kernel_launch(void* const* d_in, const int* in_sizes, int n_in,
                              void* d_out, int out_size, void* d_ws, size_t ws_size,
                              hipStream_t stream) {
    const float* x = (const float*)d_in[0];
    const float* wih[4] = { (const float*)d_in[1], (const float*)d_in[5], (const float*)d_in[9],  (const float*)d_in[13] };
    const float* whh[4] = { (const float*)d_in[2], (const float*)d_in[6], (const float*)d_in[10], (const float*)d_in[14] };
    const float* bih[4] = { (const float*)d_in[3], (const float*)d_in[7], (const float*)d_in[11], (const float*)d_in[15] };
    const float* bhh[4] = { (const float*)d_in[4], (const float*)d_in[8], (const float*)d_in[12], (const float*)d_in[16] };
    const float* lin_w = (const float*)d_in[17];
    const float* lin_b = (const float*)d_in[18];
    float* ws = (float*)d_ws;

    float* xg4   = ws + OFF_XG;
    float* yA    = ws + OFF_YA;
    float* yB    = ws + OFF_YB;
    float* wihT  = ws + OFF_WIHT;
    float* whhT  = ws + OFF_WHHT;
    float* bsum  = ws + OFF_BSUM;
    float* h0T   = ws + OFF_STATE;
    float* c0T   = h0T + BATCH * HDIM;
    float* h1T   = c0T + BATCH * HDIM;
    float* c1T   = h1T + BATCH * HDIM;

    for (int l = 0; l < 4; ++l) {
        int K = (l == 0) ? IDIM : HDIM;
        prep_wih<<<dim3((1024 * K + 255) / 256), 256, 0, stream>>>(wih[l], wihT + (size_t)l * 262144, K);
        prep_whh<<<dim3(1024), 256, 0, stream>>>(whh[l], whhT + (size_t)l * 262144);
        prep_bias<<<dim3(4), 256, 0, stream>>>(bih[l], bhh[l], bsum + l * 1024);
    }

    dim3 pgrid(256, 8);
    dim3 rgrid(32);

    proj_kernel<<<pgrid, 256, 0, stream>>>(x, IDIM, 1, wihT + 0 * 262144, bsum + 0 * 1024, xg4);
    rec_kernel<<<rgrid, 512, 0, stream>>>(xg4, whhT + 0 * 262144, yA, nullptr, nullptr, h0T, c0T);

    proj_kernel<<<pgrid, 256, 0, stream>>>(yA, HDIM, 0, wihT + 1 * 262144, bsum + 1 * 1024, xg4);
    rec_kernel<<<rgrid, 512, 0, stream>>>(xg4, whhT + 1 * 262144, yB, nullptr, nullptr, h1T, c1T);

    proj_kernel<<<pgrid, 256, 0, stream>>>(yB, HDIM, 1, wihT + 2 * 262144, bsum + 2 * 1024, xg4);
    rec_kernel<<<rgrid, 512, 0, stream>>>(xg4, whhT + 2 * 262144, yA, h0T, c0T, nullptr, nullptr);

    proj_kernel<<<pgrid, 256, 0, stream>>>(yA, HDIM, 0, wihT + 3 * 262144, bsum + 3 * 1024, xg4);
    rec_kernel<<<rgrid, 512, 0, stream>>>(xg4, whhT + 3 * 262144, yB, h1T, c1T, nullptr, nullptr);

    head_kernel<<<dim3(BATCH), 256, 0, stream>>>(yB, lin_w, lin_b, (float*)d_out);
}

// Round 3
// 14527.310 us; speedup vs baseline: 6.4973x; 6.4973x over previous
//
#include <hip/hip_runtime.h>
#include <math.h>

#define HDIM 256
#define BATCH 64
#define TLEN 512
#define IDIM 64

typedef __attribute__((ext_vector_type(8))) short s16x8;
typedef __attribute__((ext_vector_type(4))) float f32x4;

// ---------------- ws layout (float offsets) ----------------
// xg4:  [64][512][1024] gate-interleaved (j*4+g)
// yA/yB:[64][512][256]
// wihT: 4 x [1024][256] fp32 (layer0 K=64)
// whi/wlo: 4 x [1024][256] bf16 (ushort) hi/lo split of whh, layout = original rows (g*256+j)
// bsum: 4 x [1024]
// states h0T,c0T,h1T,c1T: [64][256]
// hxp:  [2][64][256] u32 packed (hi16|lo16) h exchange
// ctr:  [4 layers][4 groups][513] int
static const size_t OFF_XG    = 0;
static const size_t OFF_YA    = 33554432;
static const size_t OFF_YB    = OFF_YA + 8388608;          // 41943040
static const size_t OFF_WIHT  = OFF_YB + 8388608;          // 50331648
static const size_t OFF_WHI   = OFF_WIHT + 1048576;        // 51380224 (524288 floats = 4x262144 ushort)
static const size_t OFF_WLO   = OFF_WHI + 524288;          // 51904512
static const size_t OFF_BSUM  = OFF_WLO + 524288;          // 52428800
static const size_t OFF_STATE = OFF_BSUM + 4096;           // 52432896
static const size_t OFF_HXP   = OFF_STATE + 65536;         // 52498432 (32768 u32)
static const size_t OFF_CTR   = OFF_HXP + 32768;           // 52531200 (8208 ints)

__device__ __forceinline__ float sig_(float x) { return 1.f / (1.f + __expf(-x)); }
__device__ __forceinline__ float tanh_(float x) { float e = __expf(2.f * x); return 1.f - 2.f / (e + 1.f); }

// RNE fp32 -> bf16 hi + bf16 lo, packed (hi<<16)|lo. Finite inputs only.
__device__ __forceinline__ unsigned int packhl(float h) {
    unsigned int u = __float_as_uint(h);
    unsigned int hb = (u + 0x7fffu + ((u >> 16) & 1u)) >> 16;
    float r = h - __uint_as_float(hb << 16);
    unsigned int ur = __float_as_uint(r);
    unsigned int lb = (ur + 0x7fffu + ((ur >> 16) & 1u)) >> 16;
    return (hb << 16) | (lb & 0xffffu);
}

// -------- prep --------
__global__ void prep_wih(const float* __restrict__ w, float* __restrict__ wt, int K) {
    int idx = blockIdx.x * 256 + threadIdx.x;
    if (idx >= 1024 * K) return;
    int n = idx / K, k = idx - n * K;
    int j = n >> 2, g = n & 3;
    wt[idx] = w[(g * 256 + j) * K + k];
}

__global__ void prep_whh_split(const float* __restrict__ w,
                               unsigned short* __restrict__ hi, unsigned short* __restrict__ lo) {
    int idx = blockIdx.x * 256 + threadIdx.x;    // 262144
    float v = w[idx];
    unsigned int u = __float_as_uint(v);
    unsigned int hb = (u + 0x7fffu + ((u >> 16) & 1u)) >> 16;
    float r = v - __uint_as_float(hb << 16);
    unsigned int ur = __float_as_uint(r);
    unsigned int lb = (ur + 0x7fffu + ((ur >> 16) & 1u)) >> 16;
    hi[idx] = (unsigned short)hb;
    lo[idx] = (unsigned short)lb;
}

__global__ void prep_bias(const float* __restrict__ bi, const float* __restrict__ bh,
                          float* __restrict__ bs) {
    int n = blockIdx.x * 256 + threadIdx.x;
    int j = n >> 2, g = n & 3;
    bs[n] = bi[g * 256 + j] + bh[g * 256 + j];
}

// -------- projection GEMM (round-1, proven) --------
__global__ __launch_bounds__(256) void proj_kernel(
    const float* __restrict__ A, int K, int doRelu,
    const float* __restrict__ Wt, const float* __restrict__ bsum,
    float* __restrict__ out)
{
    __shared__ float As[16][128];
    __shared__ float Bs[16][128];
    const int tid = threadIdx.x;
    const int m0 = blockIdx.x * 128;
    const int n0 = blockIdx.y * 128;
    const int tx = tid & 15, ty = tid >> 4;

    float acc[8][8];
#pragma unroll
    for (int i = 0; i < 8; ++i)
#pragma unroll
        for (int j = 0; j < 8; ++j) acc[i][j] = 0.f;

    for (int kt = 0; kt < K; kt += 16) {
#pragma unroll
        for (int l = 0; l < 2; ++l) {
            int f = tid * 2 + l;
            int r = f >> 2;
            int c = (f & 3) << 2;
            float4 v = *(const float4*)&A[(size_t)(m0 + r) * K + kt + c];
            if (doRelu) {
                v.x = fmaxf(v.x, 0.f); v.y = fmaxf(v.y, 0.f);
                v.z = fmaxf(v.z, 0.f); v.w = fmaxf(v.w, 0.f);
            }
            As[c + 0][r] = v.x; As[c + 1][r] = v.y; As[c + 2][r] = v.z; As[c + 3][r] = v.w;
            float4 w = *(const float4*)&Wt[(size_t)(n0 + r) * K + kt + c];
            Bs[c + 0][r] = w.x; Bs[c + 1][r] = w.y; Bs[c + 2][r] = w.z; Bs[c + 3][r] = w.w;
        }
        __syncthreads();
#pragma unroll
        for (int kk = 0; kk < 16; ++kk) {
            float a[8], bb[8];
            *(float4*)&a[0]  = *(const float4*)&As[kk][ty * 8];
            *(float4*)&a[4]  = *(const float4*)&As[kk][ty * 8 + 4];
            *(float4*)&bb[0] = *(const float4*)&Bs[kk][tx * 8];
            *(float4*)&bb[4] = *(const float4*)&Bs[kk][tx * 8 + 4];
#pragma unroll
            for (int i = 0; i < 8; ++i)
#pragma unroll
                for (int j = 0; j < 8; ++j) acc[i][j] = fmaf(a[i], bb[j], acc[i][j]);
        }
        __syncthreads();
    }

    float bsv[8];
#pragma unroll
    for (int j = 0; j < 8; ++j) bsv[j] = bsum[n0 + tx * 8 + j];
#pragma unroll
    for (int i = 0; i < 8; ++i) {
        size_t row = (size_t)(m0 + ty * 8 + i);
        float4 o1 = { acc[i][0] + bsv[0], acc[i][1] + bsv[1], acc[i][2] + bsv[2], acc[i][3] + bsv[3] };
        float4 o2 = { acc[i][4] + bsv[4], acc[i][5] + bsv[5], acc[i][6] + bsv[6], acc[i][7] + bsv[7] };
        *(float4*)&out[row * 1024 + n0 + tx * 8]     = o1;
        *(float4*)&out[row * 1024 + n0 + tx * 8 + 4] = o2;
    }
}

// -------- cooperative persistent-weight recurrence --------
// 32 WGs x 256 thr. group gid = bid&3 (16 batches), j-slice wgj = bid>>2 (32 j).
// Wave w = gate w; holds B = whh[gate][256k][32 j-cols] as split-bf16 MFMA
// fragments in VGPRs permanently. Per step: all-WG h exchange via hxp
// (packed hi/lo bf16, parity double-buffered) + per-group counters.
__global__ __launch_bounds__(256, 1) void rec_coop(
    const float* __restrict__ xg4,
    const unsigned short* __restrict__ whi, const unsigned short* __restrict__ wlo,
    float* __restrict__ y,
    const float* __restrict__ h_init, const float* __restrict__ c_init,
    float* __restrict__ h_save, float* __restrict__ c_save,
    unsigned int* __restrict__ hxp, int* __restrict__ ctr)
{
    __shared__ float gatesm[2112];   // [b 16][jj 33-padded][g 4]
    const int tid  = threadIdx.x;
    const int lane = tid & 63;
    const int g    = tid >> 6;               // wave id = gate (i,f,gc,o)
    const int gid  = blockIdx.x & 3;         // batch group
    const int wgj  = blockIdx.x >> 2;        // j-slice
    const int bbase = gid * 16;
    const int jbase = wgj * 32;
    const int l15 = lane & 15, l4 = lane >> 4;
    int* cnt = ctr + gid * 513;

    // ---- persistent B fragments: bhi/blo[nt][kt], col = jbase+nt*16+l15, k = kt*32+l4*8 ----
    s16x8 bhi0[8], bhi1[8], blo0[8], blo1[8];
    {
        size_t r0 = (size_t)(g * 256 + jbase + l15) * 256 + l4 * 8;
        size_t r1 = (size_t)(g * 256 + jbase + 16 + l15) * 256 + l4 * 8;
#pragma unroll
        for (int kt = 0; kt < 8; ++kt) {
            bhi0[kt] = *(const s16x8*)(whi + r0 + kt * 32);
            bhi1[kt] = *(const s16x8*)(whi + r1 + kt * 32);
            blo0[kt] = *(const s16x8*)(wlo + r0 + kt * 32);
            blo1[kt] = *(const s16x8*)(wlo + r1 + kt * 32);
        }
    }

    // ---- per-thread outputs: (b = tid&15, j = tid>>4 and +16) ----
    const int ob = tid & 15;
    const int oj = tid >> 4;
    float c0 = 0.f, c1 = 0.f, h0 = 0.f, h1 = 0.f;
    if (h_init != nullptr) {
        h0 = h_init[(bbase + ob) * 256 + jbase + oj];
        h1 = h_init[(bbase + ob) * 256 + jbase + oj + 16];
        c0 = c_init[(bbase + ob) * 256 + jbase + oj];
        c1 = c_init[(bbase + ob) * 256 + jbase + oj + 16];
    }
    // publish h_0 into parity 0
    hxp[(size_t)(bbase + ob) * 256 + jbase + oj]      = packhl(h0);
    hxp[(size_t)(bbase + ob) * 256 + jbase + oj + 16] = packhl(h1);
    __syncthreads();
    if (tid == 0) {
        __threadfence();
        __hip_atomic_fetch_add(&cnt[0], 1, __ATOMIC_RELEASE, __HIP_MEMORY_SCOPE_AGENT);
    }

    const float* xgb = xg4 + (size_t)(bbase + ob) * TLEN * 1024 + (size_t)(jbase + oj) * 4;
    float* yb = y + (size_t)(bbase + ob) * TLEN * 256 + jbase + oj;

    for (int t = 0; t < TLEN; ++t) {
        // wait for h_t published by all 8 WGs of this group
        while (__hip_atomic_load(&cnt[t], __ATOMIC_RELAXED, __HIP_MEMORY_SCOPE_AGENT) < 8) {
            __builtin_amdgcn_s_sleep(1);
        }
        __threadfence();   // acquire: invalidate stale cached h lines

        const unsigned int* hp = hxp + (size_t)(t & 1) * 16384
                                 + (size_t)(bbase + l15) * 256 + l4 * 8;

        f32x4 a00 = {0,0,0,0}, a10 = {0,0,0,0};
        f32x4 a01 = {0,0,0,0}, a11 = {0,0,0,0};
        f32x4 a02 = {0,0,0,0}, a12 = {0,0,0,0};
#pragma unroll
        for (int kt = 0; kt < 8; ++kt) {
            uint4 u0 = *(const uint4*)(hp + kt * 32);
            uint4 u1 = *(const uint4*)(hp + kt * 32 + 4);
            union { unsigned int u[4]; s16x8 v; } ah, al;
            ah.u[0] = (u0.x >> 16) | (u0.y & 0xffff0000u);
            ah.u[1] = (u0.z >> 16) | (u0.w & 0xffff0000u);
            ah.u[2] = (u1.x >> 16) | (u1.y & 0xffff0000u);
            ah.u[3] = (u1.z >> 16) | (u1.w & 0xffff0000u);
            al.u[0] = (u0.x & 0xffffu) | (u0.y << 16);
            al.u[1] = (u0.z & 0xffffu) | (u0.w << 16);
            al.u[2] = (u1.x & 0xffffu) | (u1.y << 16);
            al.u[3] = (u1.z & 0xffffu) | (u1.w << 16);
            a00 = __builtin_amdgcn_mfma_f32_16x16x32_bf16(ah.v, bhi0[kt], a00, 0, 0, 0);
            a10 = __builtin_amdgcn_mfma_f32_16x16x32_bf16(ah.v, bhi1[kt], a10, 0, 0, 0);
            a01 = __builtin_amdgcn_mfma_f32_16x16x32_bf16(al.v, bhi0[kt], a01, 0, 0, 0);
            a11 = __builtin_amdgcn_mfma_f32_16x16x32_bf16(al.v, bhi1[kt], a11, 0, 0, 0);
            a02 = __builtin_amdgcn_mfma_f32_16x16x32_bf16(ah.v, blo0[kt], a02, 0, 0, 0);
            a12 = __builtin_amdgcn_mfma_f32_16x16x32_bf16(ah.v, blo1[kt], a12, 0, 0, 0);
        }
        f32x4 s0 = a00 + a01 + a02;
        f32x4 s1 = a10 + a11 + a12;

        // exchange gates across waves via LDS: row=(l4*4+r) is batch, col=jj, slot=g
#pragma unroll
        for (int r = 0; r < 4; ++r) {
            gatesm[((l4 * 4 + r) * 33 + l15) * 4 + g]      = s0[r];
            gatesm[((l4 * 4 + r) * 33 + 16 + l15) * 4 + g] = s1[r];
        }
        __syncthreads();

        float4 gt0 = *(const float4*)&gatesm[(ob * 33 + oj) * 4];
        float4 gt1 = *(const float4*)&gatesm[(ob * 33 + oj + 16) * 4];
        float4 xv0 = *(const float4*)(xgb + (size_t)t * 1024);
        float4 xv1 = *(const float4*)(xgb + (size_t)t * 1024 + 64);

        float ig = sig_(gt0.x + xv0.x);
        float fg = sig_(gt0.y + xv0.y);
        float gg = tanh_(gt0.z + xv0.z);
        float og = sig_(gt0.w + xv0.w);
        c0 = fmaf(fg, c0, ig * gg);
        h0 = og * tanh_(c0);

        ig = sig_(gt1.x + xv1.x);
        fg = sig_(gt1.y + xv1.y);
        gg = tanh_(gt1.z + xv1.z);
        og = sig_(gt1.w + xv1.w);
        c1 = fmaf(fg, c1, ig * gg);
        h1 = og * tanh_(c1);

        yb[(size_t)t * 256]      = h0;
        yb[(size_t)t * 256 + 16] = h1;

        size_t hx = (size_t)((t + 1) & 1) * 16384 + (size_t)(bbase + ob) * 256 + jbase + oj;
        hxp[hx]      = packhl(h0);
        hxp[hx + 16] = packhl(h1);

        __syncthreads();   // drains all threads' stores (vmcnt 0) + LDS reads done
        if (tid == 0) {
            __threadfence();
            __hip_atomic_fetch_add(&cnt[t + 1], 1, __ATOMIC_RELEASE, __HIP_MEMORY_SCOPE_AGENT);
        }
    }

    if (h_save != nullptr) {
        h_save[(bbase + ob) * 256 + jbase + oj]      = h0;
        h_save[(bbase + ob) * 256 + jbase + oj + 16] = h1;
        c_save[(bbase + ob) * 256 + jbase + oj]      = c0;
        c_save[(bbase + ob) * 256 + jbase + oj + 16] = c1;
    }
}

// -------- head --------
__global__ __launch_bounds__(256) void head_kernel(const float* __restrict__ y3,
    const float* __restrict__ lin_w, const float* __restrict__ lin_b, float* __restrict__ out)
{
    int b = blockIdx.x;
    int tid = threadIdx.x;
    float v = y3[((size_t)b * TLEN + (TLEN - 1)) * HDIM + tid] * lin_w[tid];
#pragma unroll
    for (int o = 32; o > 0; o >>= 1) v += __shfl_down(v, o);
    __shared__ float red[4];
    int wid = tid >> 6, lane = tid & 63;
    if (lane == 0) red[wid] = v;
    __syncthreads();
    if (tid == 0) out[b] = red[0] + red[1] + red[2] + red[3] + lin_b[0];
}

extern "C" void kernel_launch(void* const* d_in, const int* in_sizes, int n_in,
                              void* d_out, int out_size, void* d_ws, size_t ws_size,
                              hipStream_t stream) {
    const float* x = (const float*)d_in[0];
    const float* wih[4] = { (const float*)d_in[1], (const float*)d_in[5], (const float*)d_in[9],  (const float*)d_in[13] };
    const float* whh[4] = { (const float*)d_in[2], (const float*)d_in[6], (const float*)d_in[10], (const float*)d_in[14] };
    const float* bih[4] = { (const float*)d_in[3], (const float*)d_in[7], (const float*)d_in[11], (const float*)d_in[15] };
    const float* bhh[4] = { (const float*)d_in[4], (const float*)d_in[8], (const float*)d_in[12], (const float*)d_in[16] };
    const float* lin_w = (const float*)d_in[17];
    const float* lin_b = (const float*)d_in[18];
    float* ws = (float*)d_ws;

    float* xg4  = ws + OFF_XG;
    float* yA   = ws + OFF_YA;
    float* yB   = ws + OFF_YB;
    float* wihT = ws + OFF_WIHT;
    unsigned short* whiB = (unsigned short*)(ws + OFF_WHI);
    unsigned short* wloB = (unsigned short*)(ws + OFF_WLO);
    float* bsum = ws + OFF_BSUM;
    float* h0T  = ws + OFF_STATE;
    float* c0T  = h0T + BATCH * HDIM;
    float* h1T  = c0T + BATCH * HDIM;
    float* c1T  = h1T + BATCH * HDIM;
    unsigned int* hxp = (unsigned int*)(ws + OFF_HXP);
    int* ctr = (int*)(ws + OFF_CTR);

    // zero sync counters (graph-capture-safe)
    hipMemsetAsync(ctr, 0, 4 * 4 * 513 * sizeof(int), stream);

    for (int l = 0; l < 4; ++l) {
        int K = (l == 0) ? IDIM : HDIM;
        prep_wih<<<dim3((1024 * K + 255) / 256), 256, 0, stream>>>(wih[l], wihT + (size_t)l * 262144, K);
        prep_whh_split<<<dim3(1024), 256, 0, stream>>>(whh[l], whiB + (size_t)l * 262144, wloB + (size_t)l * 262144);
        prep_bias<<<dim3(4), 256, 0, stream>>>(bih[l], bhh[l], bsum + l * 1024);
    }

    dim3 pgrid(256, 8);
    dim3 rgrid(32);

    proj_kernel<<<pgrid, 256, 0, stream>>>(x, IDIM, 1, wihT + 0 * 262144, bsum + 0 * 1024, xg4);
    rec_coop<<<rgrid, 256, 0, stream>>>(xg4, whiB + 0 * 262144, wloB + 0 * 262144, yA,
                                        nullptr, nullptr, h0T, c0T, hxp, ctr + 0 * 2052);

    proj_kernel<<<pgrid, 256, 0, stream>>>(yA, HDIM, 0, wihT + 1 * 262144, bsum + 1 * 1024, xg4);
    rec_coop<<<rgrid, 256, 0, stream>>>(xg4, whiB + 1 * 262144, wloB + 1 * 262144, yB,
                                        nullptr, nullptr, h1T, c1T, hxp, ctr + 1 * 2052);

    proj_kernel<<<pgrid, 256, 0, stream>>>(yB, HDIM, 1, wihT + 2 * 262144, bsum + 2 * 1024, xg4);
    rec_coop<<<rgrid, 256, 0, stream>>>(xg4, whiB + 2 * 262144, wloB + 2 * 262144, yA,
                                        h0T, c0T, nullptr, nullptr, hxp, ctr + 2 * 2052);

    proj_kernel<<<pgrid, 256, 0, stream>>>(yA, HDIM, 0, wihT + 3 * 262144, bsum + 3 * 1024, xg4);
    rec_coop<<<rgrid, 256, 0, stream>>>(xg4, whiB + 3 * 262144, wloB + 3 * 262144, yB,
                                        h1T, c1T, nullptr, nullptr, hxp, ctr + 3 * 2052);

    head_kernel<<<dim3(BATCH), 256, 0, stream>>>(yB, lin_w, lin_b, (float*)d_out);
}

// Round 4
// 11962.971 us; speedup vs baseline: 7.8900x; 1.2144x over previous
//
#include <hip/hip_runtime.h>
#include <math.h>

#define HDIM 256
#define BATCH 64
#define TLEN 512
#define IDIM 64

typedef __attribute__((ext_vector_type(8))) short s16x8;
typedef __attribute__((ext_vector_type(4))) float f32x4;

// ---------------- ws layout (float offsets) ----------------
static const size_t OFF_XG    = 0;
static const size_t OFF_YA    = 33554432;
static const size_t OFF_YB    = OFF_YA + 8388608;
static const size_t OFF_WIHT  = OFF_YB + 8388608;
static const size_t OFF_WHI   = OFF_WIHT + 1048576;
static const size_t OFF_WLO   = OFF_WHI + 524288;
static const size_t OFF_BSUM  = OFF_WLO + 524288;
static const size_t OFF_STATE = OFF_BSUM + 4096;
static const size_t OFF_HXP   = OFF_STATE + 65536;
static const size_t OFF_CTR   = OFF_HXP + 32768;

__device__ __forceinline__ float sig_(float x) { return 1.f / (1.f + __expf(-x)); }
__device__ __forceinline__ float tanh_(float x) { float e = __expf(2.f * x); return 1.f - 2.f / (e + 1.f); }

// RNE fp32 -> bf16 hi + bf16 lo, packed (hi<<16)|lo.
__device__ __forceinline__ unsigned int packhl(float h) {
    unsigned int u = __float_as_uint(h);
    unsigned int hb = (u + 0x7fffu + ((u >> 16) & 1u)) >> 16;
    float r = h - __uint_as_float(hb << 16);
    unsigned int ur = __float_as_uint(r);
    unsigned int lb = (ur + 0x7fffu + ((ur >> 16) & 1u)) >> 16;
    return (hb << 16) | (lb & 0xffffu);
}

__device__ __forceinline__ void st_llc(unsigned int* p, unsigned int v) {
    __hip_atomic_store(p, v, __ATOMIC_RELAXED, __HIP_MEMORY_SCOPE_AGENT);
}
__device__ __forceinline__ unsigned long long ld_llc8(const unsigned int* p) {
    return __hip_atomic_load((const unsigned long long*)p, __ATOMIC_RELAXED, __HIP_MEMORY_SCOPE_AGENT);
}

// -------- prep --------
__global__ void prep_wih(const float* __restrict__ w, float* __restrict__ wt, int K) {
    int idx = blockIdx.x * 256 + threadIdx.x;
    if (idx >= 1024 * K) return;
    int n = idx / K, k = idx - n * K;
    int j = n >> 2, g = n & 3;
    wt[idx] = w[(g * 256 + j) * K + k];
}

__global__ void prep_whh_split(const float* __restrict__ w,
                               unsigned short* __restrict__ hi, unsigned short* __restrict__ lo) {
    int idx = blockIdx.x * 256 + threadIdx.x;
    float v = w[idx];
    unsigned int u = __float_as_uint(v);
    unsigned int hb = (u + 0x7fffu + ((u >> 16) & 1u)) >> 16;
    float r = v - __uint_as_float(hb << 16);
    unsigned int ur = __float_as_uint(r);
    unsigned int lb = (ur + 0x7fffu + ((ur >> 16) & 1u)) >> 16;
    hi[idx] = (unsigned short)hb;
    lo[idx] = (unsigned short)lb;
}

__global__ void prep_bias(const float* __restrict__ bi, const float* __restrict__ bh,
                          float* __restrict__ bs) {
    int n = blockIdx.x * 256 + threadIdx.x;
    int j = n >> 2, g = n & 3;
    bs[n] = bi[g * 256 + j] + bh[g * 256 + j];
}

// -------- projection GEMM --------
__global__ __launch_bounds__(256) void proj_kernel(
    const float* __restrict__ A, int K, int doRelu,
    const float* __restrict__ Wt, const float* __restrict__ bsum,
    float* __restrict__ out)
{
    __shared__ float As[16][128];
    __shared__ float Bs[16][128];
    const int tid = threadIdx.x;
    const int m0 = blockIdx.x * 128;
    const int n0 = blockIdx.y * 128;
    const int tx = tid & 15, ty = tid >> 4;

    float acc[8][8];
#pragma unroll
    for (int i = 0; i < 8; ++i)
#pragma unroll
        for (int j = 0; j < 8; ++j) acc[i][j] = 0.f;

    for (int kt = 0; kt < K; kt += 16) {
#pragma unroll
        for (int l = 0; l < 2; ++l) {
            int f = tid * 2 + l;
            int r = f >> 2;
            int c = (f & 3) << 2;
            float4 v = *(const float4*)&A[(size_t)(m0 + r) * K + kt + c];
            if (doRelu) {
                v.x = fmaxf(v.x, 0.f); v.y = fmaxf(v.y, 0.f);
                v.z = fmaxf(v.z, 0.f); v.w = fmaxf(v.w, 0.f);
            }
            As[c + 0][r] = v.x; As[c + 1][r] = v.y; As[c + 2][r] = v.z; As[c + 3][r] = v.w;
            float4 w = *(const float4*)&Wt[(size_t)(n0 + r) * K + kt + c];
            Bs[c + 0][r] = w.x; Bs[c + 1][r] = w.y; Bs[c + 2][r] = w.z; Bs[c + 3][r] = w.w;
        }
        __syncthreads();
#pragma unroll
        for (int kk = 0; kk < 16; ++kk) {
            float a[8], bb[8];
            *(float4*)&a[0]  = *(const float4*)&As[kk][ty * 8];
            *(float4*)&a[4]  = *(const float4*)&As[kk][ty * 8 + 4];
            *(float4*)&bb[0] = *(const float4*)&Bs[kk][tx * 8];
            *(float4*)&bb[4] = *(const float4*)&Bs[kk][tx * 8 + 4];
#pragma unroll
            for (int i = 0; i < 8; ++i)
#pragma unroll
                for (int j = 0; j < 8; ++j) acc[i][j] = fmaf(a[i], bb[j], acc[i][j]);
        }
        __syncthreads();
    }

    float bsv[8];
#pragma unroll
    for (int j = 0; j < 8; ++j) bsv[j] = bsum[n0 + tx * 8 + j];
#pragma unroll
    for (int i = 0; i < 8; ++i) {
        size_t row = (size_t)(m0 + ty * 8 + i);
        float4 o1 = { acc[i][0] + bsv[0], acc[i][1] + bsv[1], acc[i][2] + bsv[2], acc[i][3] + bsv[3] };
        float4 o2 = { acc[i][4] + bsv[4], acc[i][5] + bsv[5], acc[i][6] + bsv[6], acc[i][7] + bsv[7] };
        *(float4*)&out[row * 1024 + n0 + tx * 8]     = o1;
        *(float4*)&out[row * 1024 + n0 + tx * 8 + 4] = o2;
    }
}

// -------- cooperative persistent-weight recurrence (fence-free LLC protocol) --------
// 32 WGs x 256 thr. group gid = bid&3 (16 batches), j-slice wgj = bid>>2 (32 j).
// All cross-WG data (hxp) + flags (cnt) via agent-scope RELAXED atomics (sc0 sc1,
// LLC-direct): no threadfence / buffer_wbl2 / buffer_inv anywhere. y stores are
// also write-through atomics so L2 never holds dirty lines. Ordering argument:
// __syncthreads() drains each thread's store-acks (vmcnt(0)) before tid0's
// counter add is issued; consumer h-loads physically read LLC after the poll.
__global__ __launch_bounds__(256, 1) void rec_coop(
    const float* __restrict__ xg4,
    const unsigned short* __restrict__ whi, const unsigned short* __restrict__ wlo,
    float* __restrict__ y,
    const float* __restrict__ h_init, const float* __restrict__ c_init,
    float* __restrict__ h_save, float* __restrict__ c_save,
    unsigned int* __restrict__ hxp, int* __restrict__ ctr)
{
    __shared__ float gatesm[2112];   // [b 16][jj 33-padded][g 4]
    const int tid  = threadIdx.x;
    const int lane = tid & 63;
    const int g    = tid >> 6;
    const int gid  = blockIdx.x & 3;
    const int wgj  = blockIdx.x >> 2;
    const int bbase = gid * 16;
    const int jbase = wgj * 32;
    const int l15 = lane & 15, l4 = lane >> 4;
    int* cnt = ctr + gid * 513;

    // persistent B fragments
    s16x8 bhi0[8], bhi1[8], blo0[8], blo1[8];
    {
        size_t r0 = (size_t)(g * 256 + jbase + l15) * 256 + l4 * 8;
        size_t r1 = (size_t)(g * 256 + jbase + 16 + l15) * 256 + l4 * 8;
#pragma unroll
        for (int kt = 0; kt < 8; ++kt) {
            bhi0[kt] = *(const s16x8*)(whi + r0 + kt * 32);
            bhi1[kt] = *(const s16x8*)(whi + r1 + kt * 32);
            blo0[kt] = *(const s16x8*)(wlo + r0 + kt * 32);
            blo1[kt] = *(const s16x8*)(wlo + r1 + kt * 32);
        }
    }

    const int ob = tid & 15;
    const int oj = tid >> 4;
    float c0 = 0.f, c1 = 0.f, h0 = 0.f, h1 = 0.f;
    if (h_init != nullptr) {
        h0 = h_init[(bbase + ob) * 256 + jbase + oj];
        h1 = h_init[(bbase + ob) * 256 + jbase + oj + 16];
        c0 = c_init[(bbase + ob) * 256 + jbase + oj];
        c1 = c_init[(bbase + ob) * 256 + jbase + oj + 16];
    }
    // publish h_0 into parity 0 (LLC write-through)
    st_llc(&hxp[(size_t)(bbase + ob) * 256 + jbase + oj],      packhl(h0));
    st_llc(&hxp[(size_t)(bbase + ob) * 256 + jbase + oj + 16], packhl(h1));
    __syncthreads();   // drains store-acks of all threads
    if (tid == 0)
        __hip_atomic_fetch_add(&cnt[0], 1, __ATOMIC_RELAXED, __HIP_MEMORY_SCOPE_AGENT);

    const float* xgb = xg4 + (size_t)(bbase + ob) * TLEN * 1024 + (size_t)(jbase + oj) * 4;
    unsigned int* yb = (unsigned int*)(y + (size_t)(bbase + ob) * TLEN * 256 + jbase + oj);

    for (int t = 0; t < TLEN; ++t) {
        // own-batch x-gates: independent of handshake, issue before the spin
        float4 xv0 = *(const float4*)(xgb + (size_t)t * 1024);
        float4 xv1 = *(const float4*)(xgb + (size_t)t * 1024 + 64);

        if (tid == 0) {
            while (__hip_atomic_load(&cnt[t], __ATOMIC_RELAXED, __HIP_MEMORY_SCOPE_AGENT) < 8)
                __builtin_amdgcn_s_sleep(1);
        }
        __syncthreads();
        asm volatile("" ::: "memory");

        const unsigned int* hp = hxp + (size_t)(t & 1) * 16384
                                 + (size_t)(bbase + l15) * 256 + l4 * 8;

        f32x4 a00 = {0,0,0,0}, a10 = {0,0,0,0};
        f32x4 a01 = {0,0,0,0}, a11 = {0,0,0,0};
        f32x4 a02 = {0,0,0,0}, a12 = {0,0,0,0};
#pragma unroll
        for (int kt = 0; kt < 8; ++kt) {
            unsigned long long q0 = ld_llc8(hp + kt * 32 + 0);
            unsigned long long q1 = ld_llc8(hp + kt * 32 + 2);
            unsigned long long q2 = ld_llc8(hp + kt * 32 + 4);
            unsigned long long q3 = ld_llc8(hp + kt * 32 + 6);
            unsigned int w0 = (unsigned int)q0, w1 = (unsigned int)(q0 >> 32);
            unsigned int w2 = (unsigned int)q1, w3 = (unsigned int)(q1 >> 32);
            unsigned int w4 = (unsigned int)q2, w5 = (unsigned int)(q2 >> 32);
            unsigned int w6 = (unsigned int)q3, w7 = (unsigned int)(q3 >> 32);
            union { unsigned int u[4]; s16x8 v; } ah, al;
            ah.u[0] = (w0 >> 16) | (w1 & 0xffff0000u);
            ah.u[1] = (w2 >> 16) | (w3 & 0xffff0000u);
            ah.u[2] = (w4 >> 16) | (w5 & 0xffff0000u);
            ah.u[3] = (w6 >> 16) | (w7 & 0xffff0000u);
            al.u[0] = (w0 & 0xffffu) | (w1 << 16);
            al.u[1] = (w2 & 0xffffu) | (w3 << 16);
            al.u[2] = (w4 & 0xffffu) | (w5 << 16);
            al.u[3] = (w6 & 0xffffu) | (w7 << 16);
            a00 = __builtin_amdgcn_mfma_f32_16x16x32_bf16(ah.v, bhi0[kt], a00, 0, 0, 0);
            a10 = __builtin_amdgcn_mfma_f32_16x16x32_bf16(ah.v, bhi1[kt], a10, 0, 0, 0);
            a01 = __builtin_amdgcn_mfma_f32_16x16x32_bf16(al.v, bhi0[kt], a01, 0, 0, 0);
            a11 = __builtin_amdgcn_mfma_f32_16x16x32_bf16(al.v, bhi1[kt], a11, 0, 0, 0);
            a02 = __builtin_amdgcn_mfma_f32_16x16x32_bf16(ah.v, blo0[kt], a02, 0, 0, 0);
            a12 = __builtin_amdgcn_mfma_f32_16x16x32_bf16(ah.v, blo1[kt], a12, 0, 0, 0);
        }
        f32x4 s0 = a00 + a01 + a02;
        f32x4 s1 = a10 + a11 + a12;

#pragma unroll
        for (int r = 0; r < 4; ++r) {
            gatesm[((l4 * 4 + r) * 33 + l15) * 4 + g]      = s0[r];
            gatesm[((l4 * 4 + r) * 33 + 16 + l15) * 4 + g] = s1[r];
        }
        __syncthreads();

        float4 gt0 = *(const float4*)&gatesm[(ob * 33 + oj) * 4];
        float4 gt1 = *(const float4*)&gatesm[(ob * 33 + oj + 16) * 4];

        float ig = sig_(gt0.x + xv0.x);
        float fg = sig_(gt0.y + xv0.y);
        float gg = tanh_(gt0.z + xv0.z);
        float og = sig_(gt0.w + xv0.w);
        c0 = fmaf(fg, c0, ig * gg);
        h0 = og * tanh_(c0);

        ig = sig_(gt1.x + xv1.x);
        fg = sig_(gt1.y + xv1.y);
        gg = tanh_(gt1.z + xv1.z);
        og = sig_(gt1.w + xv1.w);
        c1 = fmaf(fg, c1, ig * gg);
        h1 = og * tanh_(c1);

        // y + next-h publish: all write-through LLC atomics (no dirty L2)
        st_llc(&yb[(size_t)t * 256],      __float_as_uint(h0));
        st_llc(&yb[(size_t)t * 256 + 16], __float_as_uint(h1));

        size_t hx = (size_t)((t + 1) & 1) * 16384 + (size_t)(bbase + ob) * 256 + jbase + oj;
        st_llc(&hxp[hx],      packhl(h0));
        st_llc(&hxp[hx + 16], packhl(h1));

        __syncthreads();   // vmcnt(0) per thread: all stores ack'd at LLC
        asm volatile("" ::: "memory");
        if (tid == 0)
            __hip_atomic_fetch_add(&cnt[t + 1], 1, __ATOMIC_RELAXED, __HIP_MEMORY_SCOPE_AGENT);
    }

    if (h_save != nullptr) {
        h_save[(bbase + ob) * 256 + jbase + oj]      = h0;
        h_save[(bbase + ob) * 256 + jbase + oj + 16] = h1;
        c_save[(bbase + ob) * 256 + jbase + oj]      = c0;
        c_save[(bbase + ob) * 256 + jbase + oj + 16] = c1;
    }
}

// -------- head --------
__global__ __launch_bounds__(256) void head_kernel(const float* __restrict__ y3,
    const float* __restrict__ lin_w, const float* __restrict__ lin_b, float* __restrict__ out)
{
    int b = blockIdx.x;
    int tid = threadIdx.x;
    float v = y3[((size_t)b * TLEN + (TLEN - 1)) * HDIM + tid] * lin_w[tid];
#pragma unroll
    for (int o = 32; o > 0; o >>= 1) v += __shfl_down(v, o);
    __shared__ float red[4];
    int wid = tid >> 6, lane = tid & 63;
    if (lane == 0) red[wid] = v;
    __syncthreads();
    if (tid == 0) out[b] = red[0] + red[1] + red[2] + red[3] + lin_b[0];
}

extern "C" void kernel_launch(void* const* d_in, const int* in_sizes, int n_in,
                              void* d_out, int out_size, void* d_ws, size_t ws_size,
                              hipStream_t stream) {
    const float* x = (const float*)d_in[0];
    const float* wih[4] = { (const float*)d_in[1], (const float*)d_in[5], (const float*)d_in[9],  (const float*)d_in[13] };
    const float* whh[4] = { (const float*)d_in[2], (const float*)d_in[6], (const float*)d_in[10], (const float*)d_in[14] };
    const float* bih[4] = { (const float*)d_in[3], (const float*)d_in[7], (const float*)d_in[11], (const float*)d_in[15] };
    const float* bhh[4] = { (const float*)d_in[4], (const float*)d_in[8], (const float*)d_in[12], (const float*)d_in[16] };
    const float* lin_w = (const float*)d_in[17];
    const float* lin_b = (const float*)d_in[18];
    float* ws = (float*)d_ws;

    float* xg4  = ws + OFF_XG;
    float* yA   = ws + OFF_YA;
    float* yB   = ws + OFF_YB;
    float* wihT = ws + OFF_WIHT;
    unsigned short* whiB = (unsigned short*)(ws + OFF_WHI);
    unsigned short* wloB = (unsigned short*)(ws + OFF_WLO);
    float* bsum = ws + OFF_BSUM;
    float* h0T  = ws + OFF_STATE;
    float* c0T  = h0T + BATCH * HDIM;
    float* h1T  = c0T + BATCH * HDIM;
    float* c1T  = h1T + BATCH * HDIM;
    unsigned int* hxp = (unsigned int*)(ws + OFF_HXP);
    int* ctr = (int*)(ws + OFF_CTR);

    hipMemsetAsync(ctr, 0, 4 * 4 * 513 * sizeof(int), stream);

    for (int l = 0; l < 4; ++l) {
        int K = (l == 0) ? IDIM : HDIM;
        prep_wih<<<dim3((1024 * K + 255) / 256), 256, 0, stream>>>(wih[l], wihT + (size_t)l * 262144, K);
        prep_whh_split<<<dim3(1024), 256, 0, stream>>>(whh[l], whiB + (size_t)l * 262144, wloB + (size_t)l * 262144);
        prep_bias<<<dim3(4), 256, 0, stream>>>(bih[l], bhh[l], bsum + l * 1024);
    }

    dim3 pgrid(256, 8);
    dim3 rgrid(32);

    proj_kernel<<<pgrid, 256, 0, stream>>>(x, IDIM, 1, wihT + 0 * 262144, bsum + 0 * 1024, xg4);
    rec_coop<<<rgrid, 256, 0, stream>>>(xg4, whiB + 0 * 262144, wloB + 0 * 262144, yA,
                                        nullptr, nullptr, h0T, c0T, hxp, ctr + 0 * 2052);

    proj_kernel<<<pgrid, 256, 0, stream>>>(yA, HDIM, 0, wihT + 1 * 262144, bsum + 1 * 1024, xg4);
    rec_coop<<<rgrid, 256, 0, stream>>>(xg4, whiB + 1 * 262144, wloB + 1 * 262144, yB,
                                        nullptr, nullptr, h1T, c1T, hxp, ctr + 1 * 2052);

    proj_kernel<<<pgrid, 256, 0, stream>>>(yB, HDIM, 1, wihT + 2 * 262144, bsum + 2 * 1024, xg4);
    rec_coop<<<rgrid, 256, 0, stream>>>(xg4, whiB + 2 * 262144, wloB + 2 * 262144, yA,
                                        h0T, c0T, nullptr, nullptr, hxp, ctr + 2 * 2052);

    proj_kernel<<<pgrid, 256, 0, stream>>>(yA, HDIM, 0, wihT + 3 * 262144, bsum + 3 * 1024, xg4);
    rec_coop<<<rgrid, 256, 0, stream>>>(xg4, whiB + 3 * 262144, wloB + 3 * 262144, yB,
                                        h1T, c1T, nullptr, nullptr, hxp, ctr + 3 * 2052);

    head_kernel<<<dim3(BATCH), 256, 0, stream>>>(yB, lin_w, lin_b, (float*)d_out);
}